// Round 5
// baseline (210.020 us; speedup 1.0000x reference)
//
#include <hip/hip_runtime.h>
#include <stdint.h>

#define NF 27
#define ND 128
#define OUTW 479          // 128 + 27*26/2
#define LDSROW 136        // 128 + 8 pad (ushort units)
#define WAVES 4
#define NB 4              // batches per wave, software-pipelined

typedef float f32x4 __attribute__((ext_vector_type(4)));
typedef short s16x8 __attribute__((ext_vector_type(8)));

__device__ __forceinline__ unsigned short f2bf(float x) {
    union { float f; uint32_t u; } c; c.f = x;
    uint32_t u = c.u;
    u += 0x7fffu + ((u >> 16) & 1u);   // RNE round to bf16
    return (unsigned short)(u >> 16);
}

// Issue batch bidx's global loads into register set R (+ bottom row): no waits.
#define ISSUE(R, B0V, B1V, bidx) do {                                         \
    long bc_ = (bidx); if (bc_ > (long)B - 1) bc_ = (long)B - 1;              \
    const float4* f4_ = (const float4*)(feat + bc_ * (NF * ND));              \
    _Pragma("unroll")                                                         \
    for (int t_ = 0; t_ < 14; ++t_) {                                         \
        int fi_ = lane + 64 * t_; if (fi_ > NF * 32 - 1) fi_ = NF * 32 - 1;   \
        R[t_] = f4_[fi_];                                                     \
    }                                                                         \
    const float* bb_ = bottom + bc_ * ND;                                     \
    B0V = bb_[lane]; B1V = bb_[lane + 64];                                    \
} while (0)

// Convert R -> wave-private LDS, Gram via MFMA, write output row for bidx.
#define PROCESS(R, B0V, B1V, bidx) do {                                       \
    if ((bidx) < (long)B) {                                                   \
        _Pragma("unroll")                                                     \
        for (int t_ = 0; t_ < 14; ++t_) {                                     \
            int fi_ = lane + 64 * t_;                                         \
            if (fi_ < NF * 32) {                                              \
                int row_ = fi_ >> 5, c4_ = fi_ & 31;                          \
                uint32_t lo_ = (uint32_t)f2bf(R[t_].x) | ((uint32_t)f2bf(R[t_].y) << 16); \
                uint32_t hi_ = (uint32_t)f2bf(R[t_].z) | ((uint32_t)f2bf(R[t_].w) << 16); \
                *(uint2*)(&sm[row_ * LDSROW + c4_ * 4]) = make_uint2(lo_, hi_); \
            }                                                                 \
        }                                                                     \
        asm volatile("s_waitcnt lgkmcnt(0)" ::: "memory");                    \
        f32x4 acc00 = {0.f,0.f,0.f,0.f};                                      \
        f32x4 acc10 = {0.f,0.f,0.f,0.f};                                      \
        f32x4 acc11 = {0.f,0.f,0.f,0.f};                                      \
        const int rsel_ = lane & 15, ksel_ = (lane >> 4) * 8;                 \
        _Pragma("unroll")                                                     \
        for (int ks_ = 0; ks_ < 4; ++ks_) {                                   \
            int k0_ = ks_ * 32 + ksel_;                                       \
            s16x8 fr0_ = *(const s16x8*)(&sm[(rsel_     ) * LDSROW + k0_]);   \
            s16x8 fr1_ = *(const s16x8*)(&sm[(rsel_ + 16) * LDSROW + k0_]);   \
            acc00 = __builtin_amdgcn_mfma_f32_16x16x32_bf16(fr0_, fr0_, acc00, 0, 0, 0); \
            acc10 = __builtin_amdgcn_mfma_f32_16x16x32_bf16(fr1_, fr0_, acc10, 0, 0, 0); \
            acc11 = __builtin_amdgcn_mfma_f32_16x16x32_bf16(fr1_, fr1_, acc11, 0, 0, 0); \
        }                                                                     \
        float* ob_ = out + (bidx) * OUTW;                                     \
        ob_[lane] = B0V; ob_[lane + 64] = B1V;                                \
        const int jj_ = lane & 15, r0_ = (lane >> 4) * 4;                     \
        _Pragma("unroll")                                                     \
        for (int e_ = 0; e_ < 4; ++e_) {                                      \
            int i0_ = r0_ + e_;                                               \
            if (jj_ < i0_) ob_[128 + (i0_ * (i0_ - 1)) / 2 + jj_] = acc00[e_];\
            int i1_ = i0_ + 16;                                               \
            if (i1_ < NF) {                                                   \
                ob_[128 + (i1_ * (i1_ - 1)) / 2 + jj_] = acc10[e_];           \
                int j1_ = jj_ + 16;                                           \
                if (j1_ < i1_) ob_[128 + (i1_ * (i1_ - 1)) / 2 + j1_] = acc11[e_]; \
            }                                                                 \
        }                                                                     \
        asm volatile("" ::: "memory"); /* keep next ds_writes after frag reads */ \
    }                                                                         \
} while (0)

// 27 rows/wave + 5-row tail pad (last wave's fr1 reads of rows 27..31 stay
// in-bounds; values garbage, feed only never-stored Gram entries).
#define LDS_ALLOC (WAVES * NF * LDSROW + 5 * LDSROW)

__global__ __launch_bounds__(256) void dot_interact_kernel(
    const float* __restrict__ feat,
    const float* __restrict__ bottom,
    float* __restrict__ out, int B)
{
    __shared__ unsigned short smem[LDS_ALLOC];
    const int tid  = threadIdx.x;
    const int w    = tid >> 6;
    const int lane = tid & 63;
    unsigned short* sm = smem + w * (NF * LDSROW);

    const long wv = (long)blockIdx.x * WAVES + w;
    const long b0 = wv * NB;
    if (b0 >= B) return;

    float4 RA[14], RB[14];
    float a0v, a1v, b0v, b1v;

    ISSUE(RA, a0v, a1v, b0);
    #pragma unroll
    for (int i = 0; i < NB; i += 2) {
        ISSUE(RB, b0v, b1v, b0 + i + 1);
        PROCESS(RA, a0v, a1v, b0 + i);
        if (i + 2 < NB) ISSUE(RA, a0v, a1v, b0 + i + 2);
        PROCESS(RB, b0v, b1v, b0 + i + 1);
    }
}

extern "C" void kernel_launch(void* const* d_in, const int* in_sizes, int n_in,
                              void* d_out, int out_size, void* d_ws, size_t ws_size,
                              hipStream_t stream) {
    const float* feat   = (const float*)d_in[0];
    const float* bottom = (const float*)d_in[1];
    float* out          = (float*)d_out;
    const int B = in_sizes[0] / (NF * ND);
    const int grid = (B + WAVES * NB - 1) / (WAVES * NB);
    dot_interact_kernel<<<grid, 256, 0, stream>>>(feat, bottom, out, B);
}

// Round 6
// 209.798 us; speedup vs baseline: 1.0011x; 1.0011x over previous
//
#include <hip/hip_runtime.h>
#include <stdint.h>

#define NF 27
#define ND 128
#define OUTW 479          // 128 + 27*26/2
#define LDSROW 136        // 128 + 8 pad (ushort units); 272 B rows -> bank spread
#define WAVES 4

typedef float f32x4 __attribute__((ext_vector_type(4)));
typedef short s16x8 __attribute__((ext_vector_type(8)));

__device__ __forceinline__ unsigned short f2bf(float x) {
    union { float f; uint32_t u; } c; c.f = x;
    uint32_t u = c.u;
    u += 0x7fffu + ((u >> 16) & 1u);   // RNE round to bf16
    return (unsigned short)(u >> 16);
}

__global__ __launch_bounds__(256) void dot_interact_kernel(
    const float* __restrict__ feat,
    const float* __restrict__ bottom,
    float* __restrict__ out, int B)
{
    __shared__ unsigned short smem[WAVES][32 * LDSROW];   // 34,816 B/block
    const int tid  = threadIdx.x;
    const int w    = tid >> 6;
    const int lane = tid & 63;
    const int b    = blockIdx.x * WAVES + w;
    unsigned short* sm = smem[w];

    if (b < B) {
        // ---- stage: 27*128 f32 -> bf16 LDS rows 0..26; rows 27..31 zeroed ----
        // Nontemporal: zero-reuse stream, don't allocate in L2 normally.
        const f32x4* f4 = (const f32x4*)(feat + (size_t)b * (NF * ND));
        #pragma unroll
        for (int t = 0; t < 16; ++t) {
            int fi  = lane + 64 * t;          // 0..1023 covers 32 rows * 32 float4
            int row = fi >> 5;
            int c4  = fi & 31;
            uint32_t lo = 0, hi = 0;
            if (fi < 864) {                   // 27 rows * 32 float4 of real data
                f32x4 v = __builtin_nontemporal_load(f4 + fi);
                lo = (uint32_t)f2bf(v[0]) | ((uint32_t)f2bf(v[1]) << 16);
                hi = (uint32_t)f2bf(v[2]) | ((uint32_t)f2bf(v[3]) << 16);
            }
            *(uint2*)(&sm[row * LDSROW + c4 * 4]) = make_uint2(lo, hi);
        }
    }
    __syncthreads();
    if (b >= B) return;

    // ---- Gram = F * F^T via mfma_f32_16x16x32_bf16 ----
    f32x4 acc00 = {0.f,0.f,0.f,0.f};
    f32x4 acc10 = {0.f,0.f,0.f,0.f};
    f32x4 acc11 = {0.f,0.f,0.f,0.f};
    const int rsel = lane & 15;
    const int ksel = (lane >> 4) * 8;
    #pragma unroll
    for (int ks = 0; ks < 4; ++ks) {
        int k0 = ks * 32 + ksel;
        s16x8 fr0 = *(const s16x8*)(&sm[(rsel     ) * LDSROW + k0]);
        s16x8 fr1 = *(const s16x8*)(&sm[(rsel + 16) * LDSROW + k0]);
        acc00 = __builtin_amdgcn_mfma_f32_16x16x32_bf16(fr0, fr0, acc00, 0, 0, 0);
        acc10 = __builtin_amdgcn_mfma_f32_16x16x32_bf16(fr1, fr0, acc10, 0, 0, 0);
        acc11 = __builtin_amdgcn_mfma_f32_16x16x32_bf16(fr1, fr1, acc11, 0, 0, 0);
    }

    float* ob = out + (size_t)b * OUTW;

    // ---- bottom_mlp_out copy (coalesced, nontemporal both ways) ----
    const float* bb = bottom + (size_t)b * ND;
    __builtin_nontemporal_store(__builtin_nontemporal_load(bb + lane),      ob + lane);
    __builtin_nontemporal_store(__builtin_nontemporal_load(bb + lane + 64), ob + lane + 64);

    // ---- tril scatter: C/D layout col=lane&15, row=(lane>>4)*4+e ----
    const int jj = lane & 15;
    const int r0 = (lane >> 4) * 4;
    #pragma unroll
    for (int e = 0; e < 4; ++e) {
        int i0 = r0 + e;                       // tile (0,0): i 0..15, j 0..15
        if (jj < i0) __builtin_nontemporal_store(acc00[e], ob + 128 + (i0 * (i0 - 1)) / 2 + jj);
        int i1 = i0 + 16;                      // tiles (1,0)/(1,1): i 16..26
        if (i1 < NF) {
            __builtin_nontemporal_store(acc10[e], ob + 128 + (i1 * (i1 - 1)) / 2 + jj);
            int j1 = jj + 16;
            if (j1 < i1) __builtin_nontemporal_store(acc11[e], ob + 128 + (i1 * (i1 - 1)) / 2 + j1);
        }
    }
}

extern "C" void kernel_launch(void* const* d_in, const int* in_sizes, int n_in,
                              void* d_out, int out_size, void* d_ws, size_t ws_size,
                              hipStream_t stream) {
    const float* feat   = (const float*)d_in[0];
    const float* bottom = (const float*)d_in[1];
    float* out          = (float*)d_out;
    const int B = in_sizes[0] / (NF * ND);
    const int grid = (B + WAVES - 1) / WAVES;
    dot_interact_kernel<<<grid, 256, 0, stream>>>(feat, bottom, out, B);
}

// Round 7
// 199.528 us; speedup vs baseline: 1.0526x; 1.0515x over previous
//
#include <hip/hip_runtime.h>
#include <stdint.h>

#define NF 27
#define ND 128
#define OUTW 479          // 128 + 27*26/2
#define LDSROW 136        // 128 + 8 pad (ushort units); 272 B rows -> bank spread
#define WAVES 4

typedef float f32x4 __attribute__((ext_vector_type(4)));
typedef short s16x8 __attribute__((ext_vector_type(8)));

__device__ __forceinline__ unsigned short f2bf(float x) {
    union { float f; uint32_t u; } c; c.f = x;
    uint32_t u = c.u;
    u += 0x7fffu + ((u >> 16) & 1u);   // RNE round to bf16
    return (unsigned short)(u >> 16);
}

__global__ __launch_bounds__(256) void dot_interact_kernel(
    const float* __restrict__ feat,
    const float* __restrict__ bottom,
    float* __restrict__ out, int B)
{
    __shared__ unsigned short smem[WAVES][32 * LDSROW];   // 34,816 B/block
    const int tid  = threadIdx.x;
    const int w    = tid >> 6;
    const int lane = tid & 63;
    const int b    = blockIdx.x * WAVES + w;
    unsigned short* sm = smem[w];

    if (b < B) {
        // ---- stage: 27*128 f32 -> bf16 LDS rows 0..26; rows 27..31 zeroed ----
        const float4* f4 = (const float4*)(feat + (size_t)b * (NF * ND));
        #pragma unroll
        for (int t = 0; t < 16; ++t) {
            int fi  = lane + 64 * t;          // 0..1023 covers 32 rows * 32 float4
            int row = fi >> 5;
            int c4  = fi & 31;
            uint32_t lo = 0, hi = 0;
            if (fi < 864) {                   // 27 rows * 32 float4 of real data
                float4 v = f4[fi];
                lo = (uint32_t)f2bf(v.x) | ((uint32_t)f2bf(v.y) << 16);
                hi = (uint32_t)f2bf(v.z) | ((uint32_t)f2bf(v.w) << 16);
            }
            *(uint2*)(&sm[row * LDSROW + c4 * 4]) = make_uint2(lo, hi);
        }
    }
    __syncthreads();
    if (b >= B) return;

    // ---- Gram = F * F^T via mfma_f32_16x16x32_bf16 ----
    // A-frag(row block) == B-frag(col block) for a Gram matrix: one load, both uses.
    f32x4 acc00 = {0.f,0.f,0.f,0.f};
    f32x4 acc10 = {0.f,0.f,0.f,0.f};
    f32x4 acc11 = {0.f,0.f,0.f,0.f};
    const int rsel = lane & 15;
    const int ksel = (lane >> 4) * 8;
    #pragma unroll
    for (int ks = 0; ks < 4; ++ks) {
        int k0 = ks * 32 + ksel;
        s16x8 fr0 = *(const s16x8*)(&sm[(rsel     ) * LDSROW + k0]);
        s16x8 fr1 = *(const s16x8*)(&sm[(rsel + 16) * LDSROW + k0]);
        acc00 = __builtin_amdgcn_mfma_f32_16x16x32_bf16(fr0, fr0, acc00, 0, 0, 0);
        acc10 = __builtin_amdgcn_mfma_f32_16x16x32_bf16(fr1, fr0, acc10, 0, 0, 0);
        acc11 = __builtin_amdgcn_mfma_f32_16x16x32_bf16(fr1, fr1, acc11, 0, 0, 0);
    }

    float* ob = out + (size_t)b * OUTW;

    // ---- bottom_mlp_out copy (coalesced) ----
    const float* bb = bottom + (size_t)b * ND;
    ob[lane]      = bb[lane];
    ob[lane + 64] = bb[lane + 64];

    // ---- tril scatter: C/D layout col=lane&15, row=(lane>>4)*4+e ----
    const int jj = lane & 15;
    const int r0 = (lane >> 4) * 4;
    #pragma unroll
    for (int e = 0; e < 4; ++e) {
        {   // tile (0,0): i in 0..15, j in 0..15
            int i = r0 + e, j = jj;
            if (j < i) ob[128 + (i * (i - 1)) / 2 + j] = acc00[e];
        }
        {   // tile (1,0): i in 16..31, j in 0..15  (j<i always)
            int i = r0 + e + 16, j = jj;
            if (i < NF) ob[128 + (i * (i - 1)) / 2 + j] = acc10[e];
        }
        {   // tile (1,1): i in 16..31, j in 16..31
            int i = r0 + e + 16, j = jj + 16;
            if (i < NF && j < i) ob[128 + (i * (i - 1)) / 2 + j] = acc11[e];
        }
    }
}

extern "C" void kernel_launch(void* const* d_in, const int* in_sizes, int n_in,
                              void* d_out, int out_size, void* d_ws, size_t ws_size,
                              hipStream_t stream) {
    const float* feat   = (const float*)d_in[0];
    const float* bottom = (const float*)d_in[1];
    float* out          = (float*)d_out;
    const int B = in_sizes[0] / (NF * ND);
    const int grid = (B + WAVES - 1) / WAVES;
    dot_interact_kernel<<<grid, 256, 0, stream>>>(feat, bottom, out, B);
}